// Round 2
// baseline (1664.492 us; speedup 1.0000x reference)
//
#include <hip/hip_runtime.h>
#include <hip/hip_bf16.h>

#define N_TOK 16384
#define DIM   1024
#define NEXP  4
#define HID   4096

typedef __attribute__((ext_vector_type(8))) short short8;
typedef __attribute__((ext_vector_type(4))) short short4v;
typedef __attribute__((ext_vector_type(4))) float float4v;

static __device__ __forceinline__ short f2bf(float f) {
  __hip_bfloat16 h = __float2bfloat16(f);
  return *reinterpret_cast<short*>(&h);
}

#define GLOAD_LDS16(gsrc, ldst)                                                            \
  __builtin_amdgcn_global_load_lds((const __attribute__((address_space(1))) void*)(gsrc),  \
                                   (__attribute__((address_space(3))) void*)(ldst), 16, 0, 0)

// ---------------- gate: softmax(concat(q,k) @ Wg + bg) ----------------
__global__ void gate_kernel(const float* __restrict__ q, const float* __restrict__ k,
                            const float* __restrict__ Wg, const float* __restrict__ bg,
                            float* __restrict__ gate) {
  const int wave = threadIdx.x >> 6, lane = threadIdx.x & 63;
  const int n = blockIdx.x * 4 + wave;
  const float* qr = q + (size_t)n * DIM;
  const float* kr = k + (size_t)n * DIM;
  float s0 = 0.f, s1 = 0.f, s2 = 0.f, s3 = 0.f;
  for (int i = 0; i < DIM / 64; ++i) {
    int d = i * 64 + lane;
    float x = qr[d];
    float4 w = *(const float4*)(Wg + (size_t)d * 4);
    s0 += x * w.x; s1 += x * w.y; s2 += x * w.z; s3 += x * w.w;
    float y = kr[d];
    float4 w2 = *(const float4*)(Wg + (size_t)(DIM + d) * 4);
    s0 += y * w2.x; s1 += y * w2.y; s2 += y * w2.z; s3 += y * w2.w;
  }
  for (int off = 32; off; off >>= 1) {
    s0 += __shfl_xor(s0, off);
    s1 += __shfl_xor(s1, off);
    s2 += __shfl_xor(s2, off);
    s3 += __shfl_xor(s3, off);
  }
  if (lane == 0) {
    float l0 = s0 + bg[0], l1 = s1 + bg[1], l2 = s2 + bg[2], l3 = s3 + bg[3];
    float m = fmaxf(fmaxf(l0, l1), fmaxf(l2, l3));
    float e0 = expf(l0 - m), e1 = expf(l1 - m), e2 = expf(l2 - m), e3 = expf(l3 - m);
    float inv = 1.f / (e0 + e1 + e2 + e3);
    float4 g; g.x = e0 * inv; g.y = e1 * inv; g.z = e2 * inv; g.w = e3 * inv;
    *(float4*)(gate + (size_t)n * 4) = g;
  }
}

// ---------------- f32 -> bf16 straight convert ----------------
__global__ void convert_bf16_kernel(const float* __restrict__ in, short* __restrict__ out, int n4) {
  int stride = gridDim.x * blockDim.x;
  for (int i = blockIdx.x * blockDim.x + threadIdx.x; i < n4; i += stride) {
    float4 v = *(const float4*)(in + (size_t)i * 4);
    short4v o;
    o[0] = f2bf(v.x); o[1] = f2bf(v.y); o[2] = f2bf(v.z); o[3] = f2bf(v.w);
    *(short4v*)(out + (size_t)i * 4) = o;
  }
}

// ---- LDS-tiled transpose+convert: in[z][R][C] f32 -> out[z_row*z + (c)][z_col*z + r] bf16 ----
__global__ void transpose_bf16_kernel(const float* __restrict__ in, short* __restrict__ out,
                                      int R, int C, int ldo, int z_row, int z_col) {
  __shared__ float tile[64][65];
  const int z = blockIdx.z;
  const float* src = in + (size_t)z * R * C;
  const int r0 = blockIdx.y * 64, c0 = blockIdx.x * 64;
  const int tc = threadIdx.x & 63, tr = threadIdx.x >> 6;
#pragma unroll
  for (int p = 0; p < 16; ++p) {
    int r = p * 4 + tr;
    tile[r][tc] = src[(size_t)(r0 + r) * C + (c0 + tc)];
  }
  __syncthreads();
#pragma unroll
  for (int p = 0; p < 16; ++p) {
    int i = p * 4 + tr;
    out[(size_t)(z * z_row + c0 + i) * ldo + z * z_col + (r0 + tc)] = f2bf(tile[tc][i]);
  }
}

// ================= 256x256 8-wave 8-phase bf16 MFMA GEMM =================
// C = A[M,K] @ Bt[N,K]^T.  BK=64, dbuf LDS, XOR-swizzled (chunk ^= row&7).
// MODE 1: OutB[row,col] = bf16( gate[row, e(col)] * relu(C + bias[ecol_off+col]) )
// MODE 2: OutF[row,col] (+)= C + sum_e gate[row,e]*bias[e*1024+col]  (e in [e0,e1))
template <int QM, bool READB, bool VMWAIT>
__device__ __forceinline__ void do_phase(const short* pA, const short* pB,
                                         short8 (&af)[4], short8 (&bf)[4],
                                         float4v (&acc)[8][4]) {
#pragma unroll
  for (int m4 = 0; m4 < 4; ++m4)
    af[m4] = *(const short8*)(pA + QM * 4096 + m4 * 1024);
  if (READB) {
#pragma unroll
    for (int n4 = 0; n4 < 4; ++n4)
      bf[n4] = *(const short8*)(pB + n4 * 1024);
  }
  __builtin_amdgcn_s_barrier();
  asm volatile("s_waitcnt lgkmcnt(0)" ::: "memory");
  __builtin_amdgcn_sched_barrier(0);
  __builtin_amdgcn_s_setprio(1);
#pragma unroll
  for (int m4 = 0; m4 < 4; ++m4)
#pragma unroll
    for (int n4 = 0; n4 < 4; ++n4)
      acc[QM * 4 + m4][n4] =
          __builtin_amdgcn_mfma_f32_16x16x32_bf16(af[m4], bf[n4], acc[QM * 4 + m4][n4], 0, 0, 0);
  __builtin_amdgcn_s_setprio(0);
  if (VMWAIT) asm volatile("s_waitcnt vmcnt(0)" ::: "memory");
  __builtin_amdgcn_sched_barrier(0);
  __builtin_amdgcn_s_barrier();
}

template <int MODE>
__global__ __launch_bounds__(512, 2)
void gemm256(const short* __restrict__ A, const short* __restrict__ Bt, int K, int ldb,
             int NTN, const float* __restrict__ bias, const float* __restrict__ gate,
             int ecol_off, int e0, int e1, int accum,
             short* __restrict__ OutB, float* __restrict__ OutF, int ldc) {
  __shared__ short sA[32768];  // 2 bufs x 256x64
  __shared__ short sB[32768];

  const int nwg = gridDim.x;
  const int NTM = nwg / NTN;
  // bijective XCD swizzle (m204)
  {
  }
  int bid = blockIdx.x;
  int qd = nwg >> 3, rm = nwg & 7;
  int xcd = bid & 7, idx = bid >> 3;
  int swz = (xcd < rm ? xcd * (qd + 1) : rm * (qd + 1) + (xcd - rm) * qd) + idx;
  // grouped 2D order: groups of 8 m-rows
  const int tpg = 8 * NTN;
  int g = swz / tpg;
  int lg = swz % tpg;
  int gm0 = g * 8;
  int gsz = NTM - gm0; if (gsz > 8) gsz = 8;
  const int tile_m = gm0 + lg % gsz;
  const int tile_n = lg / gsz;
  const int m0 = tile_m * 256;
  const int n0 = tile_n * 256;

  const int tid = threadIdx.x;
  const int lane = tid & 63;
  const int wid = tid >> 6;
  const int wm = wid >> 2, wn = wid & 3;
  const int r16 = lane & 15, kg = lane >> 4;
  const int rowL = tid >> 3;                       // staging row 0..63
  const int gc8 = (((tid & 7) ^ (rowL & 7)) * 8);  // staging src swizzled chunk (shorts)
  const int st8 = tid * 8;                         // staging LDS dst (shorts)
  // ds_read bases (shorts) — swizzle matches staging (involution)
  const int sw0 = (kg ^ (r16 & 7)) * 8;
  const int sw1 = ((4 + kg) ^ (r16 & 7)) * 8;
  const int aoff0 = (wm * 128 + r16) * 64 + sw0;
  const int aoff1 = (wm * 128 + r16) * 64 + sw1;
  const int boff0 = (wn * 64 + r16) * 64 + sw0;
  const int boff1 = (wn * 64 + r16) * 64 + sw1;

  const short* aSrc = A + (size_t)(m0 + rowL) * K + gc8;
  const short* bSrc = Bt + (size_t)(n0 + rowL) * ldb + gc8;

  float4v acc[8][4];
#pragma unroll
  for (int m = 0; m < 8; ++m)
#pragma unroll
    for (int n = 0; n < 4; ++n) acc[m][n] = (float4v)0.0f;

  // prologue: stage tile 0 into buf 0
#pragma unroll
  for (int s = 0; s < 4; ++s) {
    GLOAD_LDS16(aSrc + (size_t)s * 64 * K, sA + s * 4096 + st8);
    GLOAD_LDS16(bSrc + (size_t)s * 64 * ldb, sB + s * 4096 + st8);
  }
  asm volatile("s_waitcnt vmcnt(0)" ::: "memory");
  __builtin_amdgcn_s_barrier();

  const int T = K >> 6;
  const short* aN = aSrc + 64;
  const short* bN = bSrc + 64;
  int cur = 0;
  short8 af[4], bf[4];
  for (int t = 0; t < T; ++t) {
    const int co = cur << 14;
    const int po = (cur ^ 1) << 14;
    const bool next = (t + 1 < T);
    const short* pA0 = sA + co + aoff0;
    const short* pA1 = sA + co + aoff1;
    const short* pB0 = sB + co + boff0;
    const short* pB1 = sB + co + boff1;
    // phase 0: (qm=0, ks=0); prefetch next A slabs
    if (next) {
#pragma unroll
      for (int s = 0; s < 4; ++s) GLOAD_LDS16(aN + (size_t)s * 64 * K, sA + po + s * 4096 + st8);
    }
    do_phase<0, true, false>(pA0, pB0, af, bf, acc);
    // phase 1: (qm=1, ks=0); prefetch next B slabs
    if (next) {
#pragma unroll
      for (int s = 0; s < 4; ++s) GLOAD_LDS16(bN + (size_t)s * 64 * ldb, sB + po + s * 4096 + st8);
    }
    do_phase<1, false, false>(pA0, pB0, af, bf, acc);
    // phase 2: (qm=0, ks=1)
    do_phase<0, true, false>(pA1, pB1, af, bf, acc);
    // phase 3: (qm=1, ks=1) + tile-boundary vm drain
    do_phase<1, false, true>(pA1, pB1, af, bf, acc);
    aN += 64;
    bN += 64;
    cur ^= 1;
  }

  // epilogue: C/D layout col = lane&15, row = (lane>>4)*4 + reg  [m89/m91]
  const int rowb = m0 + wm * 128 + kg * 4;
  const int colb = n0 + wn * 64 + r16;
  if (MODE == 1) {
    const int e = (ecol_off + n0) >> 12;
#pragma unroll
    for (int m4 = 0; m4 < 8; ++m4) {
      int r0a = rowb + m4 * 16;
#pragma unroll
      for (int r = 0; r < 4; ++r) {
        int row = r0a + r;
        float g = gate[(size_t)row * 4 + e];
#pragma unroll
        for (int n4 = 0; n4 < 4; ++n4) {
          int col = colb + n4 * 16;
          float v = acc[m4][n4][r] + bias[ecol_off + col];
          OutB[(size_t)row * ldc + col] = f2bf(fmaxf(v, 0.f) * g);
        }
      }
    }
  } else {
#pragma unroll
    for (int m4 = 0; m4 < 8; ++m4) {
      int r0a = rowb + m4 * 16;
#pragma unroll
      for (int r = 0; r < 4; ++r) {
        int row = r0a + r;
        float4 gv = *(const float4*)(gate + (size_t)row * 4);
#pragma unroll
        for (int n4 = 0; n4 < 4; ++n4) {
          int col = colb + n4 * 16;
          float bt;
          if (e0 == 0 && e1 == 4)
            bt = gv.x * bias[col] + gv.y * bias[1024 + col] + gv.z * bias[2048 + col] +
                 gv.w * bias[3072 + col];
          else
            bt = gate[(size_t)row * 4 + e0] * bias[e0 * 1024 + col];
          float v = acc[m4][n4][r] + bt;
          size_t oi = (size_t)row * ldc + col;
          if (accum) v += OutF[oi];
          OutF[oi] = v;
        }
      }
    }
  }
}

extern "C" void kernel_launch(void* const* d_in, const int* in_sizes, int n_in,
                              void* d_out, int out_size, void* d_ws, size_t ws_size,
                              hipStream_t stream) {
  const float* q  = (const float*)d_in[0];
  const float* k  = (const float*)d_in[1];
  const float* W1 = (const float*)d_in[2];
  const float* b1 = (const float*)d_in[3];
  const float* W2 = (const float*)d_in[4];
  const float* b2 = (const float*)d_in[5];
  const float* Wg = (const float*)d_in[6];
  const float* bg = (const float*)d_in[7];
  float* out = (float*)d_out;

  char* ws = (char*)d_ws;
  size_t off = 0;
  float* gate = (float*)(ws + off); off += (size_t)N_TOK * 4 * sizeof(float);
  short* qb   = (short*)(ws + off); off += (size_t)N_TOK * DIM * 2;
  short* W1t  = (short*)(ws + off); off += (size_t)NEXP * (size_t)DIM * HID * 2;   // [E*H][D]
  short* W2t2 = (short*)(ws + off); off += (size_t)NEXP * (size_t)HID * DIM * 2;   // [D][E*H]
  const size_t fixed = off;

  gate_kernel<<<dim3(N_TOK / 4), dim3(256), 0, stream>>>(q, k, Wg, bg, gate);
  convert_bf16_kernel<<<dim3(2048), dim3(256), 0, stream>>>(q, qb, N_TOK * DIM / 4);
  // W1 [E][D][H] -> W1t [E*H][D]
  transpose_bf16_kernel<<<dim3(HID / 64, DIM / 64, NEXP), dim3(256), 0, stream>>>(
      W1, W1t, DIM, HID, DIM, HID, 0);
  // W2 [E][H][D] -> W2t2 [D][E*H]
  transpose_bf16_kernel<<<dim3(DIM / 64, HID / 64, NEXP), dim3(256), 0, stream>>>(
      W2, W2t2, HID, DIM, NEXP * HID, 0, HID);

  size_t avail = (ws_size > fixed) ? ws_size - fixed : 0;
  const size_t hs_concat = (size_t)N_TOK * (NEXP * HID) * 2;  // 512 MB

  if (avail >= hs_concat) {
    short* Hs = (short*)(ws + fixed);  // [N_TOK][E*H]
    gemm256<1><<<dim3((N_TOK / 256) * (NEXP * HID / 256)), dim3(512), 0, stream>>>(
        qb, W1t, DIM, DIM, NEXP * HID / 256, b1, gate, 0, 0, 0, 0, Hs, nullptr, NEXP * HID);
    gemm256<2><<<dim3((N_TOK / 256) * (DIM / 256)), dim3(512), 0, stream>>>(
        Hs, W2t2, NEXP * HID, NEXP * HID, DIM / 256, b2, gate, 0, 0, 4, 0, nullptr, out, DIM);
  } else {
    // per-expert fallback with row chunking
    short* Hs = (short*)(ws + fixed);  // [mc][H]
    long long mc = (long long)(avail / ((size_t)HID * 2));
    mc &= ~255LL;
    if (mc < 256) mc = 256;
    if (mc > N_TOK) mc = N_TOK;
    for (int cb = 0; cb < N_TOK; cb += (int)mc) {
      int rows = (N_TOK - cb < (int)mc) ? (N_TOK - cb) : (int)mc;
      int NTM = rows / 256;
      for (int e = 0; e < NEXP; ++e) {
        gemm256<1><<<dim3(NTM * (HID / 256)), dim3(512), 0, stream>>>(
            qb + (size_t)cb * DIM, W1t + (size_t)e * HID * DIM, DIM, DIM, HID / 256,
            b1, gate + (size_t)cb * 4, e * HID, 0, 0, 0, Hs, nullptr, HID);
        gemm256<2><<<dim3(NTM * (DIM / 256)), dim3(512), 0, stream>>>(
            Hs, W2t2 + (size_t)e * HID, HID, NEXP * HID, DIM / 256,
            b2, gate + (size_t)cb * 4, 0, e, e + 1, (e > 0) ? 1 : 0, nullptr,
            out + (size_t)cb * DIM, DIM);
      }
    }
  }
}